// Round 9
// baseline (255.214 us; speedup 1.0000x reference)
//
#include <hip/hip_runtime.h>
#include <math.h>
#include <stdint.h>

#define HW   128
#define CIN  64
#define OC   64
#define TW   16          // pixel tile width
#define TH   4           // pixel tile height (one wave per row)
#define HLW  18          // halo width
#define HLH  6           // halo height
#define HLN  (HLW*HLH)   // 108 halo positions
#define SXR  109         // sx row stride (floats)
#define K2   9
#define KTOT (CIN*K2)    // 576
#define SOPW 54          // sopp row stride in u32 (9 kt * 6 words, 5 used + pad)

typedef __bf16  bf16x8 __attribute__((ext_vector_type(8)));
typedef float   f32x4  __attribute__((ext_vector_type(4)));
typedef uint32_t u32x4 __attribute__((ext_vector_type(4)));

__device__ __forceinline__ ushort f32_to_bf16_rne(float f) {
    union { float f; uint32_t u; } x; x.f = f;
    return (ushort)((x.u + 0x7FFF + ((x.u >> 16) & 1)) >> 16);
}
__device__ __forceinline__ float bflo(uint32_t w) { return __uint_as_float(w << 16); }
__device__ __forceinline__ float bfhi(uint32_t w) { return __uint_as_float(w & 0xffff0000u); }

#define PKBF16(dst, lo, hi) \
    asm("v_cvt_pk_bf16_f32 %0, %1, %2" : "=v"(dst) : "v"(lo), "v"(hi))

// ---- prep: WT[o][kt*64 + c] = bf16(weight[c][o][kt]) ----
__global__ void prep_weight(const float* __restrict__ w, ushort* __restrict__ wt) {
    int n = blockIdx.x * 256 + threadIdx.x;        // 0 .. 36863
    int o = n / KTOT;
    int r = n - o * KTOT;
    int kt = r >> 6;
    int c  = r & 63;
    wt[n] = f32_to_bf16_rne(w[(c * OC + o) * K2 + kt]);
}

__global__ __launch_bounds__(256)
__attribute__((amdgpu_waves_per_eu(3, 3)))
void dyf_main(const float* __restrict__ x,
              const float* __restrict__ bias,
              const float* __restrict__ op_w,
              const float* __restrict__ op_b,
              const ushort* __restrict__ wt,
              float* __restrict__ out)
{
    __shared__ float    sx[CIN * SXR];     // 27904 B
    __shared__ float    sT[HLN];           //   432 B
    __shared__ uint32_t sopp[64 * SOPW];   // 13824 B (bf16-pair packed op rows)
                                           // total 42160 B -> 3 blocks/CU (LDS)

    const int tid  = threadIdx.x;
    const int lane = tid & 63;
    const int wv   = tid >> 6;
    const int b    = blockIdx.z;
    const int h0   = blockIdx.y * TH;
    const int w0   = blockIdx.x * TW;

    // ---- Phase 1: stage x tile + halo (zero-padded, f32) ----
    {
        const float* __restrict__ xb = x + (size_t)b * CIN * HW * HW;
        #pragma unroll
        for (int it = 0; it < 27; ++it) {          // 27*256 = 6912 = CIN*HLN
            int i  = tid + it * 256;
            int c  = i / HLN;
            int r  = i - c * HLN;
            int hy = r / HLW;
            int hx = r - hy * HLW;
            int gy = h0 - 1 + hy;
            int gx = w0 - 1 + hx;
            float v = 0.f;
            if ((unsigned)gy < HW && (unsigned)gx < HW)
                v = xb[c * HW * HW + gy * HW + gx];
            sx[c * SXR + r] = v;
        }
    }
    __syncthreads();

    // ---- Phase 2: T = per-position channel square-sum ----
    if (tid < HLN) {
        float s = 0.f;
        #pragma unroll 16
        for (int c = 0; c < CIN; ++c) { float v = sx[c * SXR + tid]; s += v * v; }
        sT[tid] = s;
    }
    __syncthreads();

    // ---- Phase 3: dynamic operator, bf16-pair packed.
    // Per (px,kt) 5 used words: (j0,j1)(j2,j3)(j4,j5)(j6,j7)(j8,0); diag +1 folded.
    {
        const int px = tid >> 2;                   // 0..63
        const int q  = tid & 3;
        const int py = px >> 4, pxx = px & 15;
        float nrm[9];
        #pragma unroll
        for (int j = 0; j < 9; ++j)
            nrm[j] = sqrtf(sT[(py + j / 3) * HLW + pxx + (j % 3)]);
        const int nkt = (q == 0) ? 3 : 2;
        for (int t = 0; t < 3; ++t) {
            if (t >= nkt) break;
            const int kt = (q == 0) ? ((t == 2) ? 8 : t) : (q * 2 + t);
            float tv[9];
            #pragma unroll
            for (int j = 0; j < 9; ++j) {
                const int m = j * 9 + kt;
                float a = op_b[m];
                #pragma unroll
                for (int jj = 0; jj < 9; ++jj) a += nrm[jj] * op_w[m * 9 + jj];
                tv[j] = tanhf(a);
            }
            tv[kt] += 1.0f;                        // fold "+xu" into diagonal
            const float fz = 0.0f;
            uint32_t pw0, pw1, pw2, pw3, pw4;
            PKBF16(pw0, tv[0], tv[1]);
            PKBF16(pw1, tv[2], tv[3]);
            PKBF16(pw2, tv[4], tv[5]);
            PKBF16(pw3, tv[6], tv[7]);
            PKBF16(pw4, tv[8], fz);
            uint32_t* d = &sopp[px * SOPW + kt * 6];
            d[0] = pw0; d[1] = pw1; d[2] = pw2; d[3] = pw3; d[4] = pw4;
        }
    }
    __syncthreads();

    // ---- Phase 4+5 fused, kt-outer: per (chalf, kt) build one B-fragment
    // and consume it immediately with 4 MFMA. No zh/ow arrays live.
    // Wave wv owns pixel row py=wv; lane: pxx=lane&15 (pixel col), g=lane>>4.
    // Slot s = 2*kt + chalf holds k = s*32 + g*8 + i -> c = chalf*32+g*8+i. 
    const int pxx = lane & 15;
    const int g   = lane >> 4;
    const int py  = wv;
    const uint32_t* __restrict__ oprow = &sopp[(wv * 16 + pxx) * SOPW];

    f32x4 acc[4];
    #pragma unroll
    for (int mr = 0; mr < 4; ++mr) acc[mr] = f32x4{0.f, 0.f, 0.f, 0.f};

    #pragma unroll
    for (int chalf = 0; chalf < 2; ++chalf) {
        // xu for this half's 8 channels (72 regs), loaded once
        float xu[8][9];
        #pragma unroll
        for (int cc = 0; cc < 8; ++cc) {
            const int c = chalf * 32 + g * 8 + cc;
            #pragma unroll
            for (int r = 0; r < 3; ++r) {
                const int pos = c * SXR + (py + r) * HLW + pxx;
                xu[cc][3 * r + 0] = sx[pos];
                xu[cc][3 * r + 1] = sx[pos + 1];
                xu[cc][3 * r + 2] = sx[pos + 2];
            }
        }
        #pragma unroll
        for (int kt = 0; kt < 9; ++kt) {
            // op row for this tap (5 words, ≤2-way banks, 4 g-groups broadcast)
            const uint2 a  = *reinterpret_cast<const uint2*>(oprow + kt * 6);
            const uint2 cw = *reinterpret_cast<const uint2*>(oprow + kt * 6 + 2);
            const uint32_t e = oprow[kt * 6 + 4];
            float opv[9];
            opv[0] = bflo(a.x);  opv[1] = bfhi(a.x);
            opv[2] = bflo(a.y);  opv[3] = bfhi(a.y);
            opv[4] = bflo(cw.x); opv[5] = bfhi(cw.x);
            opv[6] = bflo(cw.y); opv[7] = bfhi(cw.y);
            opv[8] = bflo(e);

            uint32_t pk0, pk1, pk2, pk3;
            {
                float y0 = 0.f, y1 = 0.f, y2 = 0.f, y3 = 0.f;
                float y4 = 0.f, y5 = 0.f, y6 = 0.f, y7 = 0.f;
                #pragma unroll
                for (int j = 0; j < 9; ++j) {
                    y0 += xu[0][j] * opv[j];  y1 += xu[1][j] * opv[j];
                    y2 += xu[2][j] * opv[j];  y3 += xu[3][j] * opv[j];
                    y4 += xu[4][j] * opv[j];  y5 += xu[5][j] * opv[j];
                    y6 += xu[6][j] * opv[j];  y7 += xu[7][j] * opv[j];
                }
                PKBF16(pk0, y0, y1);
                PKBF16(pk1, y2, y3);
                PKBF16(pk2, y4, y5);
                PKBF16(pk3, y6, y7);
            }
            u32x4 fr; fr[0] = pk0; fr[1] = pk1; fr[2] = pk2; fr[3] = pk3;
            const bf16x8 bfr = __builtin_bit_cast(bf16x8, fr);
            const int s = 2 * kt + chalf;
            #pragma unroll
            for (int mr = 0; mr < 4; ++mr) {
                const bf16x8 af = *reinterpret_cast<const bf16x8*>(
                    wt + (mr * 16 + pxx) * KTOT + s * 32 + g * 8);
                acc[mr] = __builtin_amdgcn_mfma_f32_16x16x32_bf16(af, bfr, acc[mr], 0, 0, 0);
            }
        }
    }

    // ---- epilogue: D row m = o = mr*16 + g*4 + ii ; col n = pxx ; pixel row wv ----
    #pragma unroll
    for (int mr = 0; mr < 4; ++mr) {
        #pragma unroll
        for (int ii = 0; ii < 4; ++ii) {
            const int o = mr * 16 + g * 4 + ii;
            out[(((size_t)b * OC + o) * HW + (h0 + wv)) * HW + w0 + pxx]
                = acc[mr][ii] + bias[o];
        }
    }
}

extern "C" void kernel_launch(void* const* d_in, const int* in_sizes, int n_in,
                              void* d_out, int out_size, void* d_ws, size_t ws_size,
                              hipStream_t stream) {
    const float* x      = (const float*)d_in[0];
    const float* weight = (const float*)d_in[1];
    const float* bias   = (const float*)d_in[2];
    const float* op_w   = (const float*)d_in[3];
    const float* op_b   = (const float*)d_in[4];
    float*  out = (float*)d_out;
    ushort* wt  = (ushort*)d_ws;                   // 73728 B

    prep_weight<<<dim3((OC * KTOT) / 256), dim3(256), 0, stream>>>(weight, wt);

    dim3 grid(HW / TW, HW / TH, 8);                // (8, 32, 8) = 2048 blocks
    dyf_main<<<grid, dim3(256), 0, stream>>>(x, bias, op_w, op_b, wt, out);
}

// Round 10
// 227.139 us; speedup vs baseline: 1.1236x; 1.1236x over previous
//
#include <hip/hip_runtime.h>
#include <math.h>
#include <stdint.h>

#define HW   128
#define CIN  64
#define OC   64
#define TW   16          // pixel tile width
#define TH   4           // pixel tile height (one wave per row)
#define HLW  18          // halo width
#define HLH  6           // halo height
#define HLN  (HLW*HLH)   // 108 halo positions
#define SXR  109         // sx row stride (floats)
#define K2   9
#define KTOT (CIN*K2)    // 576
#define SOPW 118         // sopp row stride in u32 (54 used; padded to lift LDS
                         // into the 2-block/CU regime where the allocator
                         // grants ~128 VGPRs instead of 84+spill: rounds 0/3/4
                         // vs 6/8/9 evidence)

typedef __bf16  bf16x8 __attribute__((ext_vector_type(8)));
typedef float   f32x4  __attribute__((ext_vector_type(4)));
typedef uint32_t u32x4 __attribute__((ext_vector_type(4)));

__device__ __forceinline__ ushort f32_to_bf16_rne(float f) {
    union { float f; uint32_t u; } x; x.f = f;
    return (ushort)((x.u + 0x7FFF + ((x.u >> 16) & 1)) >> 16);
}
__device__ __forceinline__ float bflo(uint32_t w) { return __uint_as_float(w << 16); }
__device__ __forceinline__ float bfhi(uint32_t w) { return __uint_as_float(w & 0xffff0000u); }

#define PKBF16(dst, lo, hi) \
    asm("v_cvt_pk_bf16_f32 %0, %1, %2" : "=v"(dst) : "v"(lo), "v"(hi))

// ---- prep: WT[o][kt*64 + c] = bf16(weight[c][o][kt]) ----
__global__ void prep_weight(const float* __restrict__ w, ushort* __restrict__ wt) {
    int n = blockIdx.x * 256 + threadIdx.x;        // 0 .. 36863
    int o = n / KTOT;
    int r = n - o * KTOT;
    int kt = r >> 6;
    int c  = r & 63;
    wt[n] = f32_to_bf16_rne(w[(c * OC + o) * K2 + kt]);
}

__global__ __launch_bounds__(256, 2)
void dyf_main(const float* __restrict__ x,
              const float* __restrict__ bias,
              const float* __restrict__ op_w,
              const float* __restrict__ op_b,
              const ushort* __restrict__ wt,
              float* __restrict__ out)
{
    __shared__ float    sx[CIN * SXR];     // 27904 B
    __shared__ float    sT[HLN];           //   432 B
    __shared__ uint32_t sopp[64 * SOPW];   // 30208 B (54 used/row, padded)
                                           // total 58544 B -> 2 blocks/CU

    const int tid  = threadIdx.x;
    const int lane = tid & 63;
    const int wv   = tid >> 6;
    const int b    = blockIdx.z;
    const int h0   = blockIdx.y * TH;
    const int w0   = blockIdx.x * TW;

    // ---- Phase 1: stage x tile + halo (zero-padded, f32) ----
    {
        const float* __restrict__ xb = x + (size_t)b * CIN * HW * HW;
        #pragma unroll
        for (int it = 0; it < 27; ++it) {          // 27*256 = 6912 = CIN*HLN
            int i  = tid + it * 256;
            int c  = i / HLN;
            int r  = i - c * HLN;
            int hy = r / HLW;
            int hx = r - hy * HLW;
            int gy = h0 - 1 + hy;
            int gx = w0 - 1 + hx;
            float v = 0.f;
            if ((unsigned)gy < HW && (unsigned)gx < HW)
                v = xb[c * HW * HW + gy * HW + gx];
            sx[c * SXR + r] = v;
        }
    }
    __syncthreads();

    // ---- Phase 2: T = per-position channel square-sum ----
    if (tid < HLN) {
        float s = 0.f;
        #pragma unroll 16
        for (int c = 0; c < CIN; ++c) { float v = sx[c * SXR + tid]; s += v * v; }
        sT[tid] = s;
    }
    __syncthreads();

    // ---- Phase 3: dynamic operator, bf16-pair packed.
    // Per (px,kt) 5 used words: (j0,j1)(j2,j3)(j4,j5)(j6,j7)(j8,0); diag +1 folded.
    {
        const int px = tid >> 2;                   // 0..63
        const int q  = tid & 3;
        const int py = px >> 4, pxx = px & 15;
        float nrm[9];
        #pragma unroll
        for (int j = 0; j < 9; ++j)
            nrm[j] = sqrtf(sT[(py + j / 3) * HLW + pxx + (j % 3)]);
        const int nkt = (q == 0) ? 3 : 2;
        for (int t = 0; t < 3; ++t) {
            if (t >= nkt) break;
            const int kt = (q == 0) ? ((t == 2) ? 8 : t) : (q * 2 + t);
            float tv[9];
            #pragma unroll
            for (int j = 0; j < 9; ++j) {
                const int m = j * 9 + kt;
                float a = op_b[m];
                #pragma unroll
                for (int jj = 0; jj < 9; ++jj) a += nrm[jj] * op_w[m * 9 + jj];
                tv[j] = tanhf(a);
            }
            tv[kt] += 1.0f;                        // fold "+xu" into diagonal
            const float fz = 0.0f;
            uint32_t pw0, pw1, pw2, pw3, pw4;
            PKBF16(pw0, tv[0], tv[1]);
            PKBF16(pw1, tv[2], tv[3]);
            PKBF16(pw2, tv[4], tv[5]);
            PKBF16(pw3, tv[6], tv[7]);
            PKBF16(pw4, tv[8], fz);
            uint32_t* d = &sopp[px * SOPW + kt * 6];
            d[0] = pw0; d[1] = pw1; d[2] = pw2; d[3] = pw3; d[4] = pw4;
        }
    }
    __syncthreads();

    // ---- Phase 4+5 fused: per channel-half, build B-fragments via two
    // 4-channel quarters (xu[4][9] live, not xu[8][9]), then 9kt x 4 MFMA.
    // Wave wv owns pixel row py=wv; lane: pxx=lane&15 (pixel col), g=lane>>4.
    // Slot s = 2*kt + chalf holds k = s*32 + g*8 + i -> c = chalf*32 + g*8 + i.
    const int pxx = lane & 15;
    const int g   = lane >> 4;
    const int py  = wv;
    const uint32_t* __restrict__ oprow = &sopp[(wv * 16 + pxx) * SOPW];

    f32x4 acc[4];
    #pragma unroll
    for (int mr = 0; mr < 4; ++mr) acc[mr] = f32x4{0.f, 0.f, 0.f, 0.f};

    #pragma unroll
    for (int chalf = 0; chalf < 2; ++chalf) {
        u32x4 zh[9];                               // fragment words for 9 kt
        #pragma unroll
        for (int qh = 0; qh < 2; ++qh) {           // 4 channels per quarter
            float xu[4][9];
            #pragma unroll
            for (int cc = 0; cc < 4; ++cc) {
                const int c = chalf * 32 + g * 8 + qh * 4 + cc;
                #pragma unroll
                for (int r = 0; r < 3; ++r) {
                    const int pos = c * SXR + (py + r) * HLW + pxx;
                    xu[cc][3 * r + 0] = sx[pos];
                    xu[cc][3 * r + 1] = sx[pos + 1];
                    xu[cc][3 * r + 2] = sx[pos + 2];
                }
            }
            #pragma unroll
            for (int kt = 0; kt < 9; ++kt) {
                const uint2 a  = *reinterpret_cast<const uint2*>(oprow + kt * 6);
                const uint2 cw = *reinterpret_cast<const uint2*>(oprow + kt * 6 + 2);
                const uint32_t e = oprow[kt * 6 + 4];
                float opv[9];
                opv[0] = bflo(a.x);  opv[1] = bfhi(a.x);
                opv[2] = bflo(a.y);  opv[3] = bfhi(a.y);
                opv[4] = bflo(cw.x); opv[5] = bfhi(cw.x);
                opv[6] = bflo(cw.y); opv[7] = bfhi(cw.y);
                opv[8] = bflo(e);
                float y0 = 0.f, y1 = 0.f, y2 = 0.f, y3 = 0.f;
                #pragma unroll
                for (int j = 0; j < 9; ++j) {
                    y0 += xu[0][j] * opv[j];  y1 += xu[1][j] * opv[j];
                    y2 += xu[2][j] * opv[j];  y3 += xu[3][j] * opv[j];
                }
                uint32_t pkA, pkB;
                PKBF16(pkA, y0, y1);               // i = qh*4+0, +1
                PKBF16(pkB, y2, y3);               // i = qh*4+2, +3
                zh[kt][qh * 2 + 0] = pkA;
                zh[kt][qh * 2 + 1] = pkB;
            }
        }
        // MFMA the 9 slots of this channel-half (A streamed from L2-hot wt)
        #pragma unroll
        for (int kt = 0; kt < 9; ++kt) {
            const int s = 2 * kt + chalf;
            const bf16x8 bfr = __builtin_bit_cast(bf16x8, zh[kt]);
            #pragma unroll
            for (int mr = 0; mr < 4; ++mr) {
                const bf16x8 af = *reinterpret_cast<const bf16x8*>(
                    wt + (mr * 16 + pxx) * KTOT + s * 32 + g * 8);
                acc[mr] = __builtin_amdgcn_mfma_f32_16x16x32_bf16(af, bfr, acc[mr], 0, 0, 0);
            }
        }
    }

    // ---- epilogue: D row m = o = mr*16 + g*4 + ii ; col n = pxx ; pixel row wv ----
    #pragma unroll
    for (int mr = 0; mr < 4; ++mr) {
        #pragma unroll
        for (int ii = 0; ii < 4; ++ii) {
            const int o = mr * 16 + g * 4 + ii;
            out[(((size_t)b * OC + o) * HW + (h0 + wv)) * HW + w0 + pxx]
                = acc[mr][ii] + bias[o];
        }
    }
}

extern "C" void kernel_launch(void* const* d_in, const int* in_sizes, int n_in,
                              void* d_out, int out_size, void* d_ws, size_t ws_size,
                              hipStream_t stream) {
    const float* x      = (const float*)d_in[0];
    const float* weight = (const float*)d_in[1];
    const float* bias   = (const float*)d_in[2];
    const float* op_w   = (const float*)d_in[3];
    const float* op_b   = (const float*)d_in[4];
    float*  out = (float*)d_out;
    ushort* wt  = (ushort*)d_ws;                   // 73728 B

    prep_weight<<<dim3((OC * KTOT) / 256), dim3(256), 0, stream>>>(weight, wt);

    dim3 grid(HW / TW, HW / TH, 8);                // (8, 32, 8) = 2048 blocks
    dyf_main<<<grid, dim3(256), 0, stream>>>(x, bias, op_w, op_b, wt, out);
}